// Round 8
// baseline (93.309 us; speedup 1.0000x reference)
//
#include <hip/hip_runtime.h>
#include <math.h>

// keypoints [B,3,M] f32, pc [B,3,N] f32.
#define BATCH 4
#define M 1024
#define N 32768
#define NSPLIT 256                 // pc chunks per batch
#define CHUNK (N / NSPLIT)         // 128 points per block (2 groups of 64)
#define TPB 256
#define KPT 4                      // 256 thr * 4 = 1024 = M
#define ROWS (BATCH * M)           // 4096

// K2 geometry: 64 blocks x 256 threads; each block owns 64 rows.
#define K2_BLOCKS 64
#define K2_TPB 256
#define K2_ROWS (ROWS / K2_BLOCKS) // 64

// ws layout (floats):
//   pws[NSPLIT][ROWS]   partial min-d2 per chunk  = 4 MiB
//   bsum[K2_BLOCKS]     per-block sums from K2
//   ticket              (as unsigned) K2 last-block counter
#define BSUM_OFF (NSPLIT * ROWS)
#define TICKET_OFF (BSUM_OFF + K2_BLOCKS)

// Broadcast a wave-uniform value from lane u via v_readlane (SGPR path).
// Round-7 post-mortem: broadcast ds_read was latency/return-bus-bound (time
// invariant to wave count, VALUBusy ~22%). readlane keeps the hot loop
// register-only: zero LDS, zero memory waits in steady state.
__device__ __forceinline__ float rlane(float v, int u) {
    return __int_as_float(__builtin_amdgcn_readlane(__float_as_int(v), u));
}

__global__ __launch_bounds__(TPB, 4) void p2p_partial(
        const float* __restrict__ kp, const float* __restrict__ pc,
        float* __restrict__ pws) {
    const int b = blockIdx.x / NSPLIT;
    const int c = blockIdx.x % NSPLIT;
    const int t = threadIdx.x;
    const int l = t & 63;

    // Reset the K2 ticket (any partial block finishes before K2 starts).
    if (blockIdx.x == 0 && t == 0)
        ((unsigned*)pws)[TICKET_OFF] = 0u;

    // Per-lane point loads: every wave holds the full 128-pt chunk as two
    // 64-pt register groups (lane l owns point g*64+l). Coalesced; waves
    // 1..3 re-read the same lines from L1.
    const float* pcb = pc + (size_t)b * 3 * N + c * CHUNK;
    float x0 = pcb[l],      y0 = pcb[N + l],      z0 = pcb[2 * N + l];
    float x1 = pcb[64 + l], y1 = pcb[N + 64 + l], z1 = pcb[2 * N + 64 + l];
    float w0 = -0.5f * fmaf(x0, x0, fmaf(y0, y0, z0 * z0));
    float w1 = -0.5f * fmaf(x1, x1, fmaf(y1, y1, z1 * z1));

    // Each thread owns KPT keypoints in registers (coalesced loads).
    const float* kpb = kp + (size_t)b * 3 * M;
    float kx[KPT], ky[KPT], kz[KPT], k2[KPT], mq[KPT];
#pragma unroll
    for (int k = 0; k < KPT; ++k) {
        int m = t + k * TPB;
        kx[k] = kpb[m];
        ky[k] = kpb[M + m];
        kz[k] = kpb[2 * M + m];
        k2[k] = fmaf(kx[k], kx[k], fmaf(ky[k], ky[k], kz[k] * kz[k]));
        mq[k] = -INFINITY;
    }

    // Hot loop: min_p ||k-p||^2 = k2 - 2*max_p(k.p - ||p||^2/2).
    // Pure VALU: per point-pair = 8 readlane + ~2 mov + 24 fma + 4 max3.
#pragma unroll 8
    for (int u = 0; u < 64; u += 2) {
        float Xa = rlane(x0, u),     Ya = rlane(y0, u);
        float Za = rlane(z0, u),     Wa = rlane(w0, u);
        float Xb = rlane(x0, u + 1), Yb = rlane(y0, u + 1);
        float Zb = rlane(z0, u + 1), Wb = rlane(w0, u + 1);
#pragma unroll
        for (int k = 0; k < KPT; ++k) {
            float qa = fmaf(kx[k], Xa, fmaf(ky[k], Ya, fmaf(kz[k], Za, Wa)));
            float qb = fmaf(kx[k], Xb, fmaf(ky[k], Yb, fmaf(kz[k], Zb, Wb)));
            mq[k] = fmaxf(fmaxf(mq[k], qa), qb);   // fuses to v_max3_f32
        }
    }
#pragma unroll 8
    for (int u = 0; u < 64; u += 2) {
        float Xa = rlane(x1, u),     Ya = rlane(y1, u);
        float Za = rlane(z1, u),     Wa = rlane(w1, u);
        float Xb = rlane(x1, u + 1), Yb = rlane(y1, u + 1);
        float Zb = rlane(z1, u + 1), Wb = rlane(w1, u + 1);
#pragma unroll
        for (int k = 0; k < KPT; ++k) {
            float qa = fmaf(kx[k], Xa, fmaf(ky[k], Ya, fmaf(kz[k], Za, Wa)));
            float qb = fmaf(kx[k], Xb, fmaf(ky[k], Yb, fmaf(kz[k], Zb, Wb)));
            mq[k] = fmaxf(fmaxf(mq[k], qa), qb);
        }
    }

    // Epilogue: d2 = k2 - 2*qmax, clamp >= 0. Plain coalesced streaming store.
    float* dst = pws + (size_t)c * ROWS + b * M;
#pragma unroll
    for (int k = 0; k < KPT; ++k) {
        float d2 = fmaxf(fmaf(-2.0f, mq[k], k2[k]), 0.0f);
        dst[t + k * TPB] = d2;
    }
}

// K2: column-min over NSPLIT partials (coalesced, latency-pipelined),
// sqrt, per-block sum; last block (ticket) folds the 64 block sums -> out.
__global__ __launch_bounds__(K2_TPB) void p2p_colmin(
        const float* __restrict__ pws, float* __restrict__ bsum,
        unsigned* __restrict__ ticket, float* __restrict__ out) {
    __shared__ float smin[4][K2_ROWS];
    __shared__ int lastflag;
    const int t = threadIdx.x;
    const int r = t & 63;
    const int g = t >> 6;                       // wave id, 0..3
    const int row = blockIdx.x * K2_ROWS + r;

    float v = INFINITY;
#pragma unroll 8
    for (int ci = 0; ci < NSPLIT / 4; ++ci) {
        int c = g * (NSPLIT / 4) + ci;
        v = fminf(v, pws[(size_t)c * ROWS + row]);
    }
    smin[g][r] = v;
    __syncthreads();

    if (t < 64) {
        float m = fminf(fminf(smin[0][t], smin[1][t]),
                        fminf(smin[2][t], smin[3][t]));
        float s = sqrtf(m);
#pragma unroll
        for (int off = 32; off > 0; off >>= 1) s += __shfl_down(s, off, 64);
        if (t == 0) {
            bsum[blockIdx.x] = s;
            __threadfence();                    // release bsum before ticket
            unsigned tk = atomicAdd(ticket, 1u);
            lastflag = (tk == K2_BLOCKS - 1) ? 1 : 0;
        }
    }
    __syncthreads();
    if (lastflag && t < 64) {
        // agent-scope loads: see all XCDs' bsum stores (released via fence)
        float s = __hip_atomic_load(&bsum[t], __ATOMIC_RELAXED,
                                    __HIP_MEMORY_SCOPE_AGENT);
#pragma unroll
        for (int off = 32; off > 0; off >>= 1) s += __shfl_down(s, off, 64);
        if (t == 0) out[0] = s / (float)ROWS;
    }
}

extern "C" void kernel_launch(void* const* d_in, const int* in_sizes, int n_in,
                              void* d_out, int out_size, void* d_ws, size_t ws_size,
                              hipStream_t stream) {
    const float* kp = (const float*)d_in[0];   // [B,3,M]
    const float* pc = (const float*)d_in[1];   // [B,3,N]
    float* out = (float*)d_out;
    float* pws = (float*)d_ws;

    p2p_partial<<<BATCH * NSPLIT, TPB, 0, stream>>>(kp, pc, pws);
    p2p_colmin<<<K2_BLOCKS, K2_TPB, 0, stream>>>(
        pws, pws + BSUM_OFF, (unsigned*)(pws + TICKET_OFF), out);
}

// Round 10
// 73.256 us; speedup vs baseline: 1.2737x; 1.2737x over previous
//
#include <hip/hip_runtime.h>
#include <math.h>

// keypoints [B,3,M] f32, pc [B,3,N] f32.
#define BATCH 4
#define M 1024
#define N 32768
#define MG 16                      // keypoints per block (SGPR-resident)
#define NMG (M / MG)               // 64 keypoint-groups per batch
#define CSPLIT 4                   // split of N
#define NPC (N / CSPLIT)           // 8192 points per block
#define TPB 256
#define ROWS (BATCH * M)           // 4096

// ws: pmin[CSPLIT][ROWS] floats = 64 KB. Every cell written exactly once by
// K1 (no init vs poison needed); K2 combines. No atomics anywhere.

// Round-8 post-mortem: broadcast-from-memory designs (LDS or readlane) never
// exceeded ~25% issue. Transposed blocking: keypoints are block-uniform ->
// SGPRs (free VALU src); points are per-lane VGPRs from coalesced float4
// global loads (L2-resident). Hot loop is pure VALU, 3 fma + 0.5 max3 /pair.
__global__ __launch_bounds__(TPB) void p2p_main(
        const float* __restrict__ kp, const float* __restrict__ pc,
        float* __restrict__ pmin) {
    const int c  = blockIdx.x & (CSPLIT - 1);
    const int mg = (blockIdx.x >> 2) & (NMG - 1);
    const int b  = blockIdx.x >> 8;
    const int t  = threadIdx.x;

    // Block-uniform keypoint loads -> scalar registers.
    const float* kpb = kp + (size_t)b * 3 * M + mg * MG;
    float skx[MG], sky[MG], skz[MG];
#pragma unroll
    for (int k = 0; k < MG; ++k) {
        skx[k] = kpb[k];
        sky[k] = kpb[M + k];
        skz[k] = kpb[2 * M + k];
    }

    float mq[MG];
#pragma unroll
    for (int k = 0; k < MG; ++k) mq[k] = -INFINITY;

    // Each thread: 32 points as 8 float4-triplets, coalesced across block.
    const float* pcb = pc + (size_t)b * 3 * N + c * NPC;
#pragma unroll 2
    for (int g = 0; g < NPC / (TPB * 4); ++g) {   // 8 iterations
        const int n = g * (TPB * 4) + t * 4;
        float4 X4 = *(const float4*)&pcb[n];
        float4 Y4 = *(const float4*)&pcb[N + n];
        float4 Z4 = *(const float4*)&pcb[2 * N + n];
        float xs[4] = {X4.x, X4.y, X4.z, X4.w};
        float ys[4] = {Y4.x, Y4.y, Y4.z, Y4.w};
        float zs[4] = {Z4.x, Z4.y, Z4.z, Z4.w};
        float w[4];
#pragma unroll
        for (int p = 0; p < 4; ++p)
            w[p] = -0.5f * fmaf(xs[p], xs[p],
                                fmaf(ys[p], ys[p], zs[p] * zs[p]));
#pragma unroll
        for (int k = 0; k < MG; ++k) {
            float q0 = fmaf(skz[k], zs[0], fmaf(sky[k], ys[0],
                        fmaf(skx[k], xs[0], w[0])));
            float q1 = fmaf(skz[k], zs[1], fmaf(sky[k], ys[1],
                        fmaf(skx[k], xs[1], w[1])));
            float q2 = fmaf(skz[k], zs[2], fmaf(sky[k], ys[2],
                        fmaf(skx[k], xs[2], w[2])));
            float q3 = fmaf(skz[k], zs[3], fmaf(sky[k], ys[3],
                        fmaf(skx[k], xs[3], w[3])));
            // fmaxf chains fuse to v_max3_f32
            mq[k] = fmaxf(fmaxf(mq[k], q0), q1);
            mq[k] = fmaxf(fmaxf(mq[k], q2), q3);
        }
    }

    // Block max-reduce per keypoint row: [16 rows][256 lanes] LDS tree.
    __shared__ float smax[MG][TPB + 1];     // +1 pad
    __shared__ float s2[MG][17];
#pragma unroll
    for (int k = 0; k < MG; ++k) smax[k][t] = mq[k];
    __syncthreads();
    {
        const int r = t >> 4, s = t & 15;   // 16 segments of 16 per row
        float m = smax[r][s * 16];
#pragma unroll
        for (int j = 1; j < 16; ++j) m = fmaxf(m, smax[r][s * 16 + j]);
        s2[r][s] = m;
    }
    __syncthreads();
    if (t < MG) {
        float m = s2[t][0];
#pragma unroll
        for (int j = 1; j < 16; ++j) m = fmaxf(m, s2[t][j]);
        // k2 per-lane (t = row): re-load this keypoint (L1-hot).
        float kx = kpb[t], ky = kpb[M + t], kz = kpb[2 * M + t];
        float k2 = fmaf(kx, kx, fmaf(ky, ky, kz * kz));
        float d2 = fmaxf(fmaf(-2.0f, m, k2), 0.0f);  // clamp >= 0
        pmin[(size_t)c * ROWS + b * M + mg * MG + t] = d2;
    }
}

// K2: combine CSPLIT partials per row, sqrt, mean. 1 block, deterministic.
__global__ __launch_bounds__(1024) void p2p_tail(
        const float* __restrict__ pmin, float* __restrict__ out) {
    __shared__ float sbuf[16];
    const int t = threadIdx.x;
    float s = 0.f;
#pragma unroll
    for (int i = 0; i < ROWS / 1024; ++i) {       // 4 rows per thread
        int r = i * 1024 + t;
        float v = fminf(fminf(pmin[r], pmin[ROWS + r]),
                        fminf(pmin[2 * ROWS + r], pmin[3 * ROWS + r]));
        s += sqrtf(v);
    }
#pragma unroll
    for (int off = 32; off > 0; off >>= 1) s += __shfl_down(s, off, 64);
    if ((t & 63) == 0) sbuf[t >> 6] = s;
    __syncthreads();
    if (t == 0) {
        float tot = 0.f;
#pragma unroll
        for (int w = 0; w < 16; ++w) tot += sbuf[w];
        out[0] = tot / (float)ROWS;
    }
}

extern "C" void kernel_launch(void* const* d_in, const int* in_sizes, int n_in,
                              void* d_out, int out_size, void* d_ws, size_t ws_size,
                              hipStream_t stream) {
    const float* kp = (const float*)d_in[0];   // [B,3,M]
    const float* pc = (const float*)d_in[1];   // [B,3,N]
    float* out = (float*)d_out;
    float* pmin = (float*)d_ws;                // 64 KB

    p2p_main<<<BATCH * NMG * CSPLIT, TPB, 0, stream>>>(kp, pc, pmin);
    p2p_tail<<<1, 1024, 0, stream>>>(pmin, out);
}

// Round 15
// 70.338 us; speedup vs baseline: 1.3266x; 1.0415x over previous
//
#include <hip/hip_runtime.h>
#include <math.h>

// keypoints [B,3,M] f32, pc [B,3,N] f32.
#define BATCH 4
#define M 1024
#define N 32768
#define MG 16                      // keypoints per block (SGPR-resident)
#define NMG (M / MG)               // 64 keypoint-groups per batch
#define CSPLIT 8                   // split of N (R10: 4 -> 8 for 8 blocks/CU)
#define NPC (N / CSPLIT)           // 4096 points per block
#define TPB 256
#define ROWS (BATCH * M)           // 4096

// ws: pmin[CSPLIT][ROWS] floats = 128 KB. Every cell written exactly once by
// K1 (no init vs poison needed); K2 combines. No atomics anywhere.

// Structure (R8/R10): keypoints are block-uniform -> SGPRs (free VALU src);
// points are per-lane VGPRs from coalesced float4 global loads (L2-resident).
// Hot loop is pure VALU, 3 fma + 0.5 max3 per pair.
// R10 post-mortem: 4 blocks/CU left ~3x slack vs VALU floor -> suspect
// latency hiding; CSPLIT=8 gives full 8 waves/SIMD occupancy.
__global__ __launch_bounds__(TPB) void p2p_main(
        const float* __restrict__ kp, const float* __restrict__ pc,
        float* __restrict__ pmin) {
    const int c  = blockIdx.x & (CSPLIT - 1);
    const int mg = (blockIdx.x >> 3) & (NMG - 1);
    const int b  = blockIdx.x >> 9;
    const int t  = threadIdx.x;

    // Block-uniform keypoint loads -> scalar registers.
    const float* kpb = kp + (size_t)b * 3 * M + mg * MG;
    float skx[MG], sky[MG], skz[MG];
#pragma unroll
    for (int k = 0; k < MG; ++k) {
        skx[k] = kpb[k];
        sky[k] = kpb[M + k];
        skz[k] = kpb[2 * M + k];
    }

    float mq[MG];
#pragma unroll
    for (int k = 0; k < MG; ++k) mq[k] = -INFINITY;

    // Each thread: 16 points as 4 float4-triplets, coalesced across block.
    const float* pcb = pc + (size_t)b * 3 * N + c * NPC;
#pragma unroll 2
    for (int g = 0; g < NPC / (TPB * 4); ++g) {   // 4 iterations
        const int n = g * (TPB * 4) + t * 4;
        float4 X4 = *(const float4*)&pcb[n];
        float4 Y4 = *(const float4*)&pcb[N + n];
        float4 Z4 = *(const float4*)&pcb[2 * N + n];
        float xs[4] = {X4.x, X4.y, X4.z, X4.w};
        float ys[4] = {Y4.x, Y4.y, Y4.z, Y4.w};
        float zs[4] = {Z4.x, Z4.y, Z4.z, Z4.w};
        float w[4];
#pragma unroll
        for (int p = 0; p < 4; ++p)
            w[p] = -0.5f * fmaf(xs[p], xs[p],
                                fmaf(ys[p], ys[p], zs[p] * zs[p]));
#pragma unroll
        for (int k = 0; k < MG; ++k) {
            float q0 = fmaf(skz[k], zs[0], fmaf(sky[k], ys[0],
                        fmaf(skx[k], xs[0], w[0])));
            float q1 = fmaf(skz[k], zs[1], fmaf(sky[k], ys[1],
                        fmaf(skx[k], xs[1], w[1])));
            float q2 = fmaf(skz[k], zs[2], fmaf(sky[k], ys[2],
                        fmaf(skx[k], xs[2], w[2])));
            float q3 = fmaf(skz[k], zs[3], fmaf(sky[k], ys[3],
                        fmaf(skx[k], xs[3], w[3])));
            // fmaxf chains fuse to v_max3_f32
            mq[k] = fmaxf(fmaxf(mq[k], q0), q1);
            mq[k] = fmaxf(fmaxf(mq[k], q2), q3);
        }
    }

    // Block max-reduce per keypoint row: [16 rows][256 lanes] LDS tree.
    __shared__ float smax[MG][TPB + 1];     // +1 pad
    __shared__ float s2[MG][17];
#pragma unroll
    for (int k = 0; k < MG; ++k) smax[k][t] = mq[k];
    __syncthreads();
    {
        const int r = t >> 4, s = t & 15;   // 16 segments of 16 per row
        float m = smax[r][s * 16];
#pragma unroll
        for (int j = 1; j < 16; ++j) m = fmaxf(m, smax[r][s * 16 + j]);
        s2[r][s] = m;
    }
    __syncthreads();
    if (t < MG) {
        float m = s2[t][0];
#pragma unroll
        for (int j = 1; j < 16; ++j) m = fmaxf(m, s2[t][j]);
        // k2 per-lane (t = row): re-load this keypoint (L1-hot).
        float kx = kpb[t], ky = kpb[M + t], kz = kpb[2 * M + t];
        float k2 = fmaf(kx, kx, fmaf(ky, ky, kz * kz));
        float d2 = fmaxf(fmaf(-2.0f, m, k2), 0.0f);  // clamp >= 0
        pmin[(size_t)c * ROWS + b * M + mg * MG + t] = d2;
    }
}

// K2: combine CSPLIT partials per row, sqrt, mean. 1 block, deterministic.
__global__ __launch_bounds__(1024) void p2p_tail(
        const float* __restrict__ pmin, float* __restrict__ out) {
    __shared__ float sbuf[16];
    const int t = threadIdx.x;
    float s = 0.f;
#pragma unroll
    for (int i = 0; i < ROWS / 1024; ++i) {       // 4 rows per thread
        int r = i * 1024 + t;
        float v = pmin[r];
#pragma unroll
        for (int c2 = 1; c2 < CSPLIT; ++c2)
            v = fminf(v, pmin[(size_t)c2 * ROWS + r]);
        s += sqrtf(v);
    }
#pragma unroll
    for (int off = 32; off > 0; off >>= 1) s += __shfl_down(s, off, 64);
    if ((t & 63) == 0) sbuf[t >> 6] = s;
    __syncthreads();
    if (t == 0) {
        float tot = 0.f;
#pragma unroll
        for (int w = 0; w < 16; ++w) tot += sbuf[w];
        out[0] = tot / (float)ROWS;
    }
}

extern "C" void kernel_launch(void* const* d_in, const int* in_sizes, int n_in,
                              void* d_out, int out_size, void* d_ws, size_t ws_size,
                              hipStream_t stream) {
    const float* kp = (const float*)d_in[0];   // [B,3,M]
    const float* pc = (const float*)d_in[1];   // [B,3,N]
    float* out = (float*)d_out;
    float* pmin = (float*)d_ws;                // 128 KB

    p2p_main<<<BATCH * NMG * CSPLIT, TPB, 0, stream>>>(kp, pc, pmin);
    p2p_tail<<<1, 1024, 0, stream>>>(pmin, out);
}